// Round 7
// baseline (361.352 us; speedup 1.0000x reference)
//
#include <hip/hip_runtime.h>

// Segmented mean: x[N][64] fp32, seg[N] int32 (sorted, contiguous), len[B] int32.
// out[B][64] = segment_sum(x) / len.
//
// Memory-bound: 264 MB read -> ~42 us floor at 6.3 TB/s (round-2 counters show
// ~half of x is L3-resident across replays: FETCH ~134 MB).
//
// Lessons encoded (rounds 0-6 post-mortems):
//  * ~280 us of dur_us is fixed harness reset cost (1 GiB ws poison fill runs
//    unconditionally at ~160 us + input restores). seg_sum is ~60-70 us.
//  * NO in-kernel device fences / done-counter last-block logic (round 2: L2
//    poisoning -> 550 us @ 0.4% VALUBusy).
//  * CACHED loads; nontemporal loads forced the HBM-miss path (round 1).
//  * MLP is NOT the limiter (round 4 null).
//  * Geometry from len[] prefix-scan overlapped with preloaded x-batch; no
//    seg[] stream; nothing gates the streaming loop (round 5: -11 us).
//  * Bigger blocks + shfl-butterfly epilogue (round 6: -5 us).
//  * THIS ROUND: single kernel. Each block scales its partial sums by
//    1/len[s] (len already in registers from the prefix scan) BEFORE the
//    global atomicAdd -- the accumulator converges directly to the mean,
//    eliminating the seg_div dispatch. Blocks widened to 2048 rows
//    (min segment ~8100 keeps the <=1-boundary invariant; N = 512*2048).

#define D 64
#define ROWS_PER_BLOCK 2048
#define NTHREADS 256

typedef float f32x4 __attribute__((ext_vector_type(4)));

__global__ __launch_bounds__(NTHREADS) void seg_mean_kernel(
    const float* __restrict__ x,
    const int*   __restrict__ seg,   // only used by the generic fallback
    const int*   __restrict__ len,
    float*       __restrict__ out,   // [B][D] fp32, pre-zeroed; becomes the mean
    int n_rows, int B)
{
    __shared__ float l0[4][D];   // per-wave reduced partials, segment s0
    __shared__ float l1[4][D];   // per-wave reduced partials, segment s0+1

    const int tid = threadIdx.x;
    const int r0  = blockIdx.x * ROWS_PER_BLOCK;
    if (r0 >= n_rows) return;   // uniform across block
    int r1 = r0 + ROWS_PER_BLOCK;
    if (r1 > n_rows) r1 = n_rows;

    // thread layout: 16 col-groups (float4) x 16 row-lanes
    // -> one wave covers 4 consecutive rows x 64 cols = 1 KB contiguous
    const int col     = (tid & 15) * 4;
    const int rowlane = tid >> 4;
    const int lane    = tid & 63;
    const int wid     = tid >> 6;

    const bool full = (r1 - r0) == ROWS_PER_BLOCK;

    // geometry input: issue the (tiny, L2-hot) len load first
    int mylen = 0;
    if (B <= 64 && lane < B) mylen = len[lane];

    // ---- preload batch 0: 8 independent 16B x-loads, gated by NOTHING ----
    const float* p = x + (size_t)(r0 + rowlane) * D + col;
    f32x4 w0{}, w1{}, w2{}, w3{}, w4{}, w5{}, w6{}, w7{};
    if (full) {
        w0 = *(const f32x4*)(p + (size_t)0 * 16 * D);
        w1 = *(const f32x4*)(p + (size_t)1 * 16 * D);
        w2 = *(const f32x4*)(p + (size_t)2 * 16 * D);
        w3 = *(const f32x4*)(p + (size_t)3 * 16 * D);
        w4 = *(const f32x4*)(p + (size_t)4 * 16 * D);
        w5 = *(const f32x4*)(p + (size_t)5 * 16 * D);
        w6 = *(const f32x4*)(p + (size_t)6 * 16 * D);
        w7 = *(const f32x4*)(p + (size_t)7 * 16 * D);
    }

    // ---- segment geometry from len[] (overlaps the loads above) ----
    // o_beg[b] = start row of segment b. s0 = segment containing r0;
    // nb = #segment starts in (r0, r1); boundary = first such start.
    int s0 = 0, nb = 2, boundary = r1;
    float inv0 = 1.0f, inv1 = 1.0f;
    if (B <= 64) {
        int incl = mylen;
        #pragma unroll
        for (int d = 1; d < 64; d <<= 1) {
            const int t = __shfl_up(incl, d, 64);
            if (lane >= d) incl += t;
        }
        const int o_beg = incl - mylen;          // pad lanes: o_beg = N
        s0 = __popcll(__ballot(o_beg <= r0)) - 1;
        const unsigned long long mb = __ballot(o_beg > r0 && o_beg < r1);
        nb = __popcll(mb);
        if (nb) boundary = __shfl(o_beg, (int)(__ffsll((long long)mb) - 1), 64);
        // segment lengths live in lane registers: pull 1/len for s0 (and s0+1)
        inv0 = 1.0f / (float)__shfl(mylen, s0, 64);
        if (nb) inv1 = 1.0f / (float)__shfl(mylen, s0 + 1, 64);
    }

    if (nb <= 1) {
        f32x4 a0 = {0.f, 0.f, 0.f, 0.f};
        f32x4 a1 = {0.f, 0.f, 0.f, 0.f};

        if (full && nb == 0) {
            // ---- fast path: pure streaming, 4 independent accumulators,
            //      128 loads/thread in 16 batches of 8 ----
            f32x4 t0 = w0, t1 = w1, t2 = w2, t3 = w3;
            t0 += w4; t1 += w5; t2 += w6; t3 += w7;
            #pragma unroll
            for (int it = 1; it < 16; ++it) {
                const float* q = p + (size_t)it * 128 * D;
                const f32x4 v0 = *(const f32x4*)(q + (size_t)0 * 16 * D);
                const f32x4 v1 = *(const f32x4*)(q + (size_t)1 * 16 * D);
                const f32x4 v2 = *(const f32x4*)(q + (size_t)2 * 16 * D);
                const f32x4 v3 = *(const f32x4*)(q + (size_t)3 * 16 * D);
                const f32x4 v4 = *(const f32x4*)(q + (size_t)4 * 16 * D);
                const f32x4 v5 = *(const f32x4*)(q + (size_t)5 * 16 * D);
                const f32x4 v6 = *(const f32x4*)(q + (size_t)6 * 16 * D);
                const f32x4 v7 = *(const f32x4*)(q + (size_t)7 * 16 * D);
                t0 += v0; t1 += v1; t2 += v2; t3 += v3;
                t0 += v4; t1 += v5; t2 += v6; t3 += v7;
            }
            a0 = (t0 + t1) + (t2 + t3);
        } else if (full) {
            // nb == 1: consume preloaded batch with predicate, then loop
            const int rbase = r0 + rowlane;
            if (rbase +   0 < boundary) a0 += w0; else a1 += w0;
            if (rbase +  16 < boundary) a0 += w1; else a1 += w1;
            if (rbase +  32 < boundary) a0 += w2; else a1 += w2;
            if (rbase +  48 < boundary) a0 += w3; else a1 += w3;
            if (rbase +  64 < boundary) a0 += w4; else a1 += w4;
            if (rbase +  80 < boundary) a0 += w5; else a1 += w5;
            if (rbase +  96 < boundary) a0 += w6; else a1 += w6;
            if (rbase + 112 < boundary) a0 += w7; else a1 += w7;
            #pragma unroll 8
            for (int r = rbase + 128; r < r1; r += 16) {
                const f32x4 v = *(const f32x4*)(x + (size_t)r * D + col);
                if (r < boundary) { a0 += v; } else { a1 += v; }
            }
        } else {
            // tail block (doesn't occur at N=1048576): predicated loop
            for (int r = r0 + rowlane; r < r1; r += 16) {
                const f32x4 v = *(const f32x4*)(x + (size_t)r * D + col);
                if (r < boundary) { a0 += v; } else { a1 += v; }
            }
        }

        // ---- epilogue: shfl butterfly over the wave's 4 row-groups ----
        // lanes l, l^16, l^32, l^48 share a col-group; after xor-16 + xor-32
        // every lane holds the wave total for its col-group.
        #pragma unroll
        for (int j = 0; j < 4; ++j) {
            a0[j] += __shfl_xor(a0[j], 16, 64);
            a0[j] += __shfl_xor(a0[j], 32, 64);
        }
        if (nb) {
            #pragma unroll
            for (int j = 0; j < 4; ++j) {
                a1[j] += __shfl_xor(a1[j], 16, 64);
                a1[j] += __shfl_xor(a1[j], 32, 64);
            }
        }
        if (lane < 16) {  // lane's col-group = lane*4; scale by 1/len HERE
            #pragma unroll
            for (int j = 0; j < 4; ++j) l0[wid][lane * 4 + j] = a0[j] * inv0;
            if (nb) {
                #pragma unroll
                for (int j = 0; j < 4; ++j) l1[wid][lane * 4 + j] = a1[j] * inv1;
            }
        }
        __syncthreads();
        if (tid < D) {
            const float s = (l0[0][tid] + l0[1][tid]) + (l0[2][tid] + l0[3][tid]);
            atomicAdd(&out[(size_t)s0 * D + tid], s);
        } else if (nb && tid < 2 * D) {
            const int c = tid - D;
            const float s = (l1[0][c] + l1[1][c]) + (l1[2][c] + l1[3][c]);
            atomicAdd(&out[(size_t)(s0 + 1) * D + c], s);
        }
    } else {
        // ---- general fallback: per-row seg[] attribution (not expected;
        //      scales each flush by 1/len[cur] so out is still the mean) ----
        f32x4 a = {0.f, 0.f, 0.f, 0.f};
        int cur = -1;
        for (int r = r0 + rowlane; r < r1; r += 16) {
            const int s = seg[r];
            const f32x4 v = *(const f32x4*)(x + (size_t)r * D + col);
            if (s != cur) {
                if (cur >= 0) {
                    const float inv = 1.0f / (float)len[cur];
                    atomicAdd(&out[(size_t)cur * D + col + 0], a.x * inv);
                    atomicAdd(&out[(size_t)cur * D + col + 1], a.y * inv);
                    atomicAdd(&out[(size_t)cur * D + col + 2], a.z * inv);
                    atomicAdd(&out[(size_t)cur * D + col + 3], a.w * inv);
                }
                a = {0.f, 0.f, 0.f, 0.f};
                cur = s;
            }
            a += v;
        }
        if (cur >= 0) {
            const float inv = 1.0f / (float)len[cur];
            atomicAdd(&out[(size_t)cur * D + col + 0], a.x * inv);
            atomicAdd(&out[(size_t)cur * D + col + 1], a.y * inv);
            atomicAdd(&out[(size_t)cur * D + col + 2], a.z * inv);
            atomicAdd(&out[(size_t)cur * D + col + 3], a.w * inv);
        }
    }
}

extern "C" void kernel_launch(void* const* d_in, const int* in_sizes, int n_in,
                              void* d_out, int out_size, void* d_ws, size_t ws_size,
                              hipStream_t stream) {
    const float* x   = (const float*)d_in[0];
    const int*   seg = (const int*)d_in[1];
    const int*   len = (const int*)d_in[2];
    float*       out = (float*)d_out;

    const int n_rows = in_sizes[1];       // N = 1048576
    const int B      = in_sizes[2];       // 64
    const int total  = B * D;             // 4096 == out_size

    // out doubles as the accumulator: zero it (out is poisoned before each call)
    hipMemsetAsync(out, 0, (size_t)total * sizeof(float), stream);

    const int grid = (n_rows + ROWS_PER_BLOCK - 1) / ROWS_PER_BLOCK;  // 512
    seg_mean_kernel<<<grid, NTHREADS, 0, stream>>>(x, seg, len, out, n_rows, B);
}

// Round 8
// 357.056 us; speedup vs baseline: 1.0120x; 1.0120x over previous
//
#include <hip/hip_runtime.h>

// Segmented mean: x[N][64] fp32, seg[N] int32 (sorted, contiguous), len[B] int32.
// out[B][64] = segment_sum(x) / len.
//
// Memory-bound: 264 MB read -> ~42 us floor at 6.3 TB/s (round-2 counters show
// ~half of x is L3-resident across replays: FETCH ~134 MB).
//
// Lessons encoded (rounds 0-7 post-mortems):
//  * ~280 us of dur_us is fixed harness reset cost (1 GiB ws poison fill runs
//    unconditionally at ~160 us + input restores). seg_sum is ~60-70 us.
//  * NO in-kernel device fences / done-counter last-block logic (round 2: L2
//    poisoning -> 550 us @ 0.4% VALUBusy).
//  * CACHED loads; nontemporal loads forced the HBM-miss path (round 1).
//  * MLP is NOT the limiter (round 4 null).
//  * Geometry from len[] prefix-scan overlapped with preloaded x-batch; no
//    seg[] stream; nothing gates the streaming loop (round 5: -11 us).
//  * 1024-row blocks + shfl-butterfly epilogue (round 6: -5 us).
//  * 2048-row blocks REGRESSED (+3.5 us, round 7): 512 blocks = 2/CU leaves
//    no scheduling slack; boundary blocks become stragglers. Stay at 4/CU.
//  * THIS ROUND: round-6 blocking (1024 rows, 1024 blocks) + round-7's
//    divide-fusion: each block scales partials by 1/len[s] (len already in
//    registers from the prefix scan) before the atomicAdd, so out converges
//    directly to the mean and the seg_div dispatch disappears.

#define D 64
#define ROWS_PER_BLOCK 1024
#define NTHREADS 256

typedef float f32x4 __attribute__((ext_vector_type(4)));

__global__ __launch_bounds__(NTHREADS) void seg_mean_kernel(
    const float* __restrict__ x,
    const int*   __restrict__ seg,   // only used by the generic fallback
    const int*   __restrict__ len,
    float*       __restrict__ out,   // [B][D] fp32, pre-zeroed; becomes the mean
    int n_rows, int B)
{
    __shared__ float l0[4][D];   // per-wave reduced partials, segment s0
    __shared__ float l1[4][D];   // per-wave reduced partials, segment s0+1

    const int tid = threadIdx.x;
    const int r0  = blockIdx.x * ROWS_PER_BLOCK;
    if (r0 >= n_rows) return;   // uniform across block
    int r1 = r0 + ROWS_PER_BLOCK;
    if (r1 > n_rows) r1 = n_rows;

    // thread layout: 16 col-groups (float4) x 16 row-lanes
    // -> one wave covers 4 consecutive rows x 64 cols = 1 KB contiguous
    const int col     = (tid & 15) * 4;
    const int rowlane = tid >> 4;
    const int lane    = tid & 63;
    const int wid     = tid >> 6;

    const bool full = (r1 - r0) == ROWS_PER_BLOCK;

    // geometry input: issue the (tiny, L2-hot) len load first
    int mylen = 0;
    if (B <= 64 && lane < B) mylen = len[lane];

    // ---- preload batch 0: 8 independent 16B x-loads, gated by NOTHING ----
    const float* p = x + (size_t)(r0 + rowlane) * D + col;
    f32x4 w0{}, w1{}, w2{}, w3{}, w4{}, w5{}, w6{}, w7{};
    if (full) {
        w0 = *(const f32x4*)(p + (size_t)0 * 16 * D);
        w1 = *(const f32x4*)(p + (size_t)1 * 16 * D);
        w2 = *(const f32x4*)(p + (size_t)2 * 16 * D);
        w3 = *(const f32x4*)(p + (size_t)3 * 16 * D);
        w4 = *(const f32x4*)(p + (size_t)4 * 16 * D);
        w5 = *(const f32x4*)(p + (size_t)5 * 16 * D);
        w6 = *(const f32x4*)(p + (size_t)6 * 16 * D);
        w7 = *(const f32x4*)(p + (size_t)7 * 16 * D);
    }

    // ---- segment geometry from len[] (overlaps the loads above) ----
    // o_beg[b] = start row of segment b. s0 = segment containing r0;
    // nb = #segment starts in (r0, r1); boundary = first such start.
    int s0 = 0, nb = 2, boundary = r1;
    float inv0 = 1.0f, inv1 = 1.0f;
    if (B <= 64) {
        int incl = mylen;
        #pragma unroll
        for (int d = 1; d < 64; d <<= 1) {
            const int t = __shfl_up(incl, d, 64);
            if (lane >= d) incl += t;
        }
        const int o_beg = incl - mylen;          // pad lanes: o_beg = N
        s0 = __popcll(__ballot(o_beg <= r0)) - 1;
        const unsigned long long mb = __ballot(o_beg > r0 && o_beg < r1);
        nb = __popcll(mb);
        if (nb) boundary = __shfl(o_beg, (int)(__ffsll((long long)mb) - 1), 64);
        // segment lengths live in lane registers: pull 1/len for s0 (and s0+1)
        inv0 = 1.0f / (float)__shfl(mylen, s0, 64);
        if (nb) inv1 = 1.0f / (float)__shfl(mylen, s0 + 1, 64);
    }

    if (nb <= 1) {
        f32x4 a0 = {0.f, 0.f, 0.f, 0.f};
        f32x4 a1 = {0.f, 0.f, 0.f, 0.f};

        if (full && nb == 0) {
            // ---- fast path: pure streaming, 4 independent accumulators,
            //      64 loads/thread in 8 batches of 8 ----
            f32x4 t0 = w0, t1 = w1, t2 = w2, t3 = w3;
            t0 += w4; t1 += w5; t2 += w6; t3 += w7;
            #pragma unroll
            for (int it = 1; it < 8; ++it) {
                const float* q = p + (size_t)it * 128 * D;
                const f32x4 v0 = *(const f32x4*)(q + (size_t)0 * 16 * D);
                const f32x4 v1 = *(const f32x4*)(q + (size_t)1 * 16 * D);
                const f32x4 v2 = *(const f32x4*)(q + (size_t)2 * 16 * D);
                const f32x4 v3 = *(const f32x4*)(q + (size_t)3 * 16 * D);
                const f32x4 v4 = *(const f32x4*)(q + (size_t)4 * 16 * D);
                const f32x4 v5 = *(const f32x4*)(q + (size_t)5 * 16 * D);
                const f32x4 v6 = *(const f32x4*)(q + (size_t)6 * 16 * D);
                const f32x4 v7 = *(const f32x4*)(q + (size_t)7 * 16 * D);
                t0 += v0; t1 += v1; t2 += v2; t3 += v3;
                t0 += v4; t1 += v5; t2 += v6; t3 += v7;
            }
            a0 = (t0 + t1) + (t2 + t3);
        } else if (full) {
            // nb == 1: consume preloaded batch with predicate, then loop
            const int rbase = r0 + rowlane;
            if (rbase +   0 < boundary) a0 += w0; else a1 += w0;
            if (rbase +  16 < boundary) a0 += w1; else a1 += w1;
            if (rbase +  32 < boundary) a0 += w2; else a1 += w2;
            if (rbase +  48 < boundary) a0 += w3; else a1 += w3;
            if (rbase +  64 < boundary) a0 += w4; else a1 += w4;
            if (rbase +  80 < boundary) a0 += w5; else a1 += w5;
            if (rbase +  96 < boundary) a0 += w6; else a1 += w6;
            if (rbase + 112 < boundary) a0 += w7; else a1 += w7;
            #pragma unroll 8
            for (int r = rbase + 128; r < r1; r += 16) {
                const f32x4 v = *(const f32x4*)(x + (size_t)r * D + col);
                if (r < boundary) { a0 += v; } else { a1 += v; }
            }
        } else {
            // tail block (doesn't occur at N=1048576): predicated loop
            for (int r = r0 + rowlane; r < r1; r += 16) {
                const f32x4 v = *(const f32x4*)(x + (size_t)r * D + col);
                if (r < boundary) { a0 += v; } else { a1 += v; }
            }
        }

        // ---- epilogue: shfl butterfly over the wave's 4 row-groups ----
        // lanes l, l^16, l^32, l^48 share a col-group; after xor-16 + xor-32
        // every lane holds the wave total for its col-group.
        #pragma unroll
        for (int j = 0; j < 4; ++j) {
            a0[j] += __shfl_xor(a0[j], 16, 64);
            a0[j] += __shfl_xor(a0[j], 32, 64);
        }
        if (nb) {
            #pragma unroll
            for (int j = 0; j < 4; ++j) {
                a1[j] += __shfl_xor(a1[j], 16, 64);
                a1[j] += __shfl_xor(a1[j], 32, 64);
            }
        }
        if (lane < 16) {  // lane's col-group = lane*4; scale by 1/len HERE
            #pragma unroll
            for (int j = 0; j < 4; ++j) l0[wid][lane * 4 + j] = a0[j] * inv0;
            if (nb) {
                #pragma unroll
                for (int j = 0; j < 4; ++j) l1[wid][lane * 4 + j] = a1[j] * inv1;
            }
        }
        __syncthreads();
        if (tid < D) {
            const float s = (l0[0][tid] + l0[1][tid]) + (l0[2][tid] + l0[3][tid]);
            atomicAdd(&out[(size_t)s0 * D + tid], s);
        } else if (nb && tid < 2 * D) {
            const int c = tid - D;
            const float s = (l1[0][c] + l1[1][c]) + (l1[2][c] + l1[3][c]);
            atomicAdd(&out[(size_t)(s0 + 1) * D + c], s);
        }
    } else {
        // ---- general fallback: per-row seg[] attribution (not expected;
        //      scales each flush by 1/len[cur] so out is still the mean) ----
        f32x4 a = {0.f, 0.f, 0.f, 0.f};
        int cur = -1;
        for (int r = r0 + rowlane; r < r1; r += 16) {
            const int s = seg[r];
            const f32x4 v = *(const f32x4*)(x + (size_t)r * D + col);
            if (s != cur) {
                if (cur >= 0) {
                    const float inv = 1.0f / (float)len[cur];
                    atomicAdd(&out[(size_t)cur * D + col + 0], a.x * inv);
                    atomicAdd(&out[(size_t)cur * D + col + 1], a.y * inv);
                    atomicAdd(&out[(size_t)cur * D + col + 2], a.z * inv);
                    atomicAdd(&out[(size_t)cur * D + col + 3], a.w * inv);
                }
                a = {0.f, 0.f, 0.f, 0.f};
                cur = s;
            }
            a += v;
        }
        if (cur >= 0) {
            const float inv = 1.0f / (float)len[cur];
            atomicAdd(&out[(size_t)cur * D + col + 0], a.x * inv);
            atomicAdd(&out[(size_t)cur * D + col + 1], a.y * inv);
            atomicAdd(&out[(size_t)cur * D + col + 2], a.z * inv);
            atomicAdd(&out[(size_t)cur * D + col + 3], a.w * inv);
        }
    }
}

extern "C" void kernel_launch(void* const* d_in, const int* in_sizes, int n_in,
                              void* d_out, int out_size, void* d_ws, size_t ws_size,
                              hipStream_t stream) {
    const float* x   = (const float*)d_in[0];
    const int*   seg = (const int*)d_in[1];
    const int*   len = (const int*)d_in[2];
    float*       out = (float*)d_out;

    const int n_rows = in_sizes[1];       // N = 1048576
    const int B      = in_sizes[2];       // 64
    const int total  = B * D;             // 4096 == out_size

    // out doubles as the accumulator: zero it (out is poisoned before each call)
    hipMemsetAsync(out, 0, (size_t)total * sizeof(float), stream);

    const int grid = (n_rows + ROWS_PER_BLOCK - 1) / ROWS_PER_BLOCK;  // 1024
    seg_mean_kernel<<<grid, NTHREADS, 0, stream>>>(x, seg, len, out, n_rows, B);
}